// Round 23
// baseline (158.861 us; speedup 1.0000x reference)
//
#include <hip/hip_runtime.h>
#include <stdint.h>

#define N_ROWS 500000
#define Q0 50000
#define Q1 10000
#define NB (Q0 + Q1)
#define NTILES (N_ROWS / 16)          // 31250 exactly

// ---- partition geometry ----
#define SH0T 9                        // table0: 512-bucket partitions
#define SH1T 8                        // table1: 256-bucket partitions
#define NP0 98                        // ceil(50000/512)
#define NP1 40                        // ceil(10000/256)
#define NPARTS (NP0 + NP1)
#define TILE_ROWS 4096
#define T_TILES ((N_ROWS + TILE_ROWS - 1) / TILE_ROWS)   // 123 per table
#define PA_THREADS 512
#define ROWS_PER_T (TILE_ROWS / PA_THREADS)   // 8

#define CHUNK 2048                    // entries per partB block
#define PSTRIDE (512 * 16 + 512)      // floats per partial block (sums + counts)
#define FXS 32768.0f                  // fixed-point scale (2^15)
#define FXSI (1.0f / 32768.0f)

typedef __attribute__((ext_vector_type(8))) short bf16x8;   // 8 bf16 (4 VGPRs)
typedef __attribute__((ext_vector_type(4))) float f32x4;

static __device__ __forceinline__ uint32_t f2bfu(float f) {
    uint32_t u = __builtin_bit_cast(uint32_t, f);
    u += 0x7fffu + ((u >> 16) & 1u);          // round-to-nearest-even
    return u >> 16;
}
static __device__ __forceinline__ short f2bf(float f) { return (short)f2bfu(f); }
static __device__ __forceinline__ float bfu2f(uint32_t u) {
    return __builtin_bit_cast(float, u << 16);
}
static __device__ __forceinline__ uint32_t pk2(float x, float y) {
    return f2bfu(x) | (f2bfu(y) << 16);
}
// HW packed RNE f32->bf16 pair (T12 primitive; no builtin on gfx950 -> asm)
static __device__ __forceinline__ uint32_t cvtpk(float lo, float hi) {
    uint32_t r;
    asm("v_cvt_pk_bf16_f32 %0, %1, %2" : "=v"(r) : "v"(lo), "v"(hi));
    return r;
}

__global__ __launch_bounds__(256) void zero_ws_kernel(uint32_t* __restrict__ p, int total) {
    int stride = gridDim.x * 256;
    for (int i = blockIdx.x * 256 + threadIdx.x; i < total; i += stride) p[i] = 0u;
}

// Pass A: partition-scatter with LDS staging -> coalesced global runs.
// 4096-row tiles, 512 threads (8 waves/CU).
__global__ __launch_bounds__(PA_THREADS) void partA_kernel(const int* __restrict__ z0,
                                                    const int* __restrict__ z1,
                                                    const float* __restrict__ emb0,
                                                    const float* __restrict__ emb1,
                                                    uint32_t* __restrict__ pid0,
                                                    uint32_t* __restrict__ pdata0,
                                                    uint32_t* __restrict__ pid1,
                                                    uint32_t* __restrict__ pdata1,
                                                    int* __restrict__ curs,
                                                    int* __restrict__ ovfcnt,
                                                    float* __restrict__ ovf,
                                                    int cap0, int cap1) {
    const bool is0 = blockIdx.x < T_TILES;
    const int tile = is0 ? blockIdx.x : blockIdx.x - T_TILES;
    const int* z = is0 ? z0 : z1;
    const float* emb = is0 ? emb0 : emb1;
    const int nparts = is0 ? NP0 : NP1;
    const int SH = is0 ? SH0T : SH1T;
    const int cap = is0 ? cap0 : cap1;
    uint32_t* pid = is0 ? pid0 : pid1;
    uint32_t* pdata = is0 ? pdata0 : pdata1;
    int* cur = curs + (is0 ? 0 : NP0);
    const int wofs = is0 ? 0 : Q0;

    __shared__ int lcnt[NP0];
    __shared__ int loff[NP0 + 1];
    __shared__ int gbase[NP0];
    extern __shared__ uint32_t dynlds[];
    uint32_t* sid = dynlds;                       // TILE_ROWS
    uint32_t* spay = dynlds + TILE_ROWS;          // TILE_ROWS*8 (128 KB)

    const int t = threadIdx.x;
    const int lane = t & 63;
    const int wv = t >> 6;
    for (int i = t; i < nparts; i += PA_THREADS) lcnt[i] = 0;
    __syncthreads();

    int bks[ROWS_PER_T], rnk[ROWS_PER_T];
    const int base = tile * TILE_ROWS;
#pragma unroll
    for (int i = 0; i < ROWS_PER_T; i++) {
        int r = base + i * PA_THREADS + t;
        if (r < N_ROWS) {
            int b = z[r];
            bks[i] = b;
            rnk[i] = atomicAdd(&lcnt[b >> SH], 1);
        } else {
            bks[i] = -1;
            rnk[i] = 0;
        }
    }
    __syncthreads();

    // ---- wave 0: shfl_up inclusive scan of lcnt -> loff (two 64-wide chunks)
    //      waves 1-2: reserve global cursor space (latency overlaps the scan)
    if (wv == 0) {
        int v = (lane < nparts) ? lcnt[lane] : 0;
#pragma unroll
        for (int off = 1; off < 64; off <<= 1) {
            int u = __shfl_up(v, off);
            if (lane >= off) v += u;
        }
        if (lane < nparts) loff[lane + 1] = v;
        if (lane == 0) loff[0] = 0;
        int tot0 = __shfl(v, 63);
        if (nparts > 64) {
            int l2 = 64 + lane;
            int w2 = (l2 < nparts) ? lcnt[l2] : 0;
#pragma unroll
            for (int off = 1; off < 64; off <<= 1) {
                int u = __shfl_up(w2, off);
                if (lane >= off) w2 += u;
            }
            w2 += tot0;
            if (l2 < nparts) loff[l2 + 1] = w2;
        }
    } else if (wv < 3) {
        int p = t - 64;
        if (p < nparts) gbase[p] = atomicAdd(&cur[p], lcnt[p]);
    }
    __syncthreads();

    // ---- place entries (bf16 payload) partition-ordered in staging
#pragma unroll
    for (int i = 0; i < ROWS_PER_T; i++) {
        if (bks[i] < 0) continue;
        int r = base + i * PA_THREADS + t;
        int p = bks[i] >> SH;
        int s = loff[p] + rnk[i];
        sid[s] = (uint32_t)bks[i];
        const float4* e = (const float4*)(emb + (size_t)r * 16);
        float4 A = e[0], B = e[1], C = e[2], D = e[3];
        uint32_t* d = &spay[s * 8];
        d[0] = pk2(A.x, A.y); d[1] = pk2(A.z, A.w);
        d[2] = pk2(B.x, B.y); d[3] = pk2(B.z, B.w);
        d[4] = pk2(C.x, C.y); d[5] = pk2(C.z, C.w);
        d[6] = pk2(D.x, D.y); d[7] = pk2(D.z, D.w);
    }
    __syncthreads();

    // ---- merged flush: one thread per slot (id + 32B payload, run-coalesced)
    const int E = loff[nparts];
    for (int s = t; s < E; s += PA_THREADS) {
        int b = (int)sid[s];
        int p = b >> SH;
        int dest = gbase[p] + (s - loff[p]);
        const uint4* sp = (const uint4*)&spay[s * 8];
        uint4 lo = sp[0], hi = sp[1];
        if (dest < cap) {
            pid[(size_t)p * cap + dest] = (uint32_t)b;
            uint4* dp = (uint4*)(pdata + ((size_t)p * cap + dest) * 8);
            dp[0] = lo; dp[1] = hi;
        } else {
            atomicAdd(&ovfcnt[b + wofs], 1);
            float* o = ovf + (size_t)(b + wofs) * 16;
            uint32_t xs[8] = {lo.x, lo.y, lo.z, lo.w, hi.x, hi.y, hi.z, hi.w};
#pragma unroll
            for (int q = 0; q < 8; q++) {
                atomicAdd(o + q * 2,     bfu2f(xs[q] & 0xffffu));
                atomicAdd(o + q * 2 + 1, bfu2f(xs[q] >> 16));
            }
        }
    }
}

// Pass B: one block per (partition, CHUNK). Batched register loads, then
// INT32 fixed-point LDS accumulation via native ds_add.
__global__ __launch_bounds__(256) void partB_kernel(const uint32_t* __restrict__ pid0,
                                                    const uint32_t* __restrict__ pdata0,
                                                    const uint32_t* __restrict__ pid1,
                                                    const uint32_t* __restrict__ pdata1,
                                                    const int* __restrict__ curs,
                                                    float* __restrict__ partials,
                                                    int cap0, int cap1,
                                                    int nc0, int nc1) {
    const int bid = blockIdx.x;
    const bool is0 = bid < NP0 * nc0;
    int lp, ck;
    if (is0) { lp = bid / nc0; ck = bid % nc0; }
    else     { int r = bid - NP0 * nc0; lp = r / nc1; ck = r % nc1; }
    const int SH = is0 ? SH0T : SH1T;
    const int NBK = 1 << SH;
    const int p = is0 ? lp : NP0 + lp;
    const int cap = is0 ? cap0 : cap1;
    const uint32_t* pi = (is0 ? pid0 : pid1) + (size_t)lp * cap;
    const uint32_t* pd = (is0 ? pdata0 : pdata1) + (size_t)lp * cap * 8;
    int n = curs[p];
    if (n > cap) n = cap;
    const int start = ck * CHUNK;
    if (start >= n) return;                        // inactive chunk: never read
    const int nslots = ((start + CHUNK < n) ? CHUNK : (n - start));
    const int fb = lp << SH;

    __shared__ int sums[512 * 16];                 // 32 KB, rotation-swizzled, fixed-point
    __shared__ int cnt[512];
    const int t = threadIdx.x;
    for (int i = t; i < NBK * 16; i += 256) sums[i] = 0;
    for (int i = t; i < NBK; i += 256) cnt[i] = 0;
    __syncthreads();

    const int half = t & 1;                        // which 4 dwords of the slot
    const int sbase = t >> 1;                      // 0..127

#pragma unroll
    for (int mg = 0; mg < 2; mg++) {
        uint4 pay[8]; int lbs[8]; bool val[8];
#pragma unroll
        for (int gi = 0; gi < 8; gi++) {
            int slot = (mg * 8 + gi) * 128 + sbase;
            bool v = slot < nslots;
            val[gi] = v;
            if (v) {
                pay[gi] = *(const uint4*)(pd + (size_t)(start + slot) * 8 + half * 4);
                lbs[gi] = (int)pi[start + slot] - fb;
            }
        }
#pragma unroll
        for (int gi = 0; gi < 8; gi++) {
            if (!val[gi]) continue;
            int lb = lbs[gi];
            int* S = &sums[lb * 16];
            int d0 = half * 8;
            uint32_t xs[4] = {pay[gi].x, pay[gi].y, pay[gi].z, pay[gi].w};
#pragma unroll
            for (int jj = 0; jj < 4; jj++) {
                int da = d0 + jj * 2, db = da + 1;
                int fa = __float2int_rn(bfu2f(xs[jj] & 0xffffu) * FXS);
                int fbv = __float2int_rn(bfu2f(xs[jj] >> 16) * FXS);
                atomicAdd(S + ((da + lb) & 15), fa);
                atomicAdd(S + ((db + lb) & 15), fbv);
            }
            if (half == 0) atomicAdd(&cnt[lb], 1);
        }
    }
    __syncthreads();

    float* P = partials + (size_t)bid * PSTRIDE;
    for (int i = t; i < NBK * 16; i += 256) {
        int lb = i >> 4, d = i & 15;
        P[i] = (float)sums[lb * 16 + ((d + lb) & 15)] * FXSI;   // unswizzle + rescale
    }
    for (int i = t; i < NBK; i += 256) P[512 * 16 + i] = (float)cnt[i];
}

// Combine: one thread per (bucket, dim-PAIR). Sum chunk partials + overflow,
// divide_no_nan, write PACKED BF16 means.
__global__ __launch_bounds__(256) void combine_kernel(const float* __restrict__ partials,
                                                      const int* __restrict__ curs,
                                                      const int* __restrict__ ovfcnt,
                                                      const float* __restrict__ ovf,
                                                      uint32_t* __restrict__ meansb,
                                                      int cap0, int cap1,
                                                      int nc0, int nc1) {
    int i = blockIdx.x * 256 + threadIdx.x;
    if (i >= NB * 8) return;
    int w = i >> 3, dp = i & 7;
    int d0 = dp * 2, d1 = d0 + 1;
    const bool is0 = w < Q0;
    const int b = is0 ? w : w - Q0;
    const int lp = b >> (is0 ? SH0T : SH1T);
    const int lb = b & (is0 ? 511 : 255);
    const int p = is0 ? lp : NP0 + lp;
    const int pb = is0 ? lp * nc0 : NP0 * nc0 + lp * nc1;
    const int cap = is0 ? cap0 : cap1;
    int n = curs[p];
    if (n > cap) n = cap;
    const int nc = (n + CHUNK - 1) / CHUNK;
    float s0 = 0.0f, s1 = 0.0f, cc = 0.0f;
    for (int k = 0; k < nc; k++) {
        const float* P = partials + (size_t)(pb + k) * PSTRIDE;
        s0 += P[lb * 16 + d0];
        s1 += P[lb * 16 + d1];
        cc += P[512 * 16 + lb];
    }
    s0 += ovf[(size_t)w * 16 + d0];
    s1 += ovf[(size_t)w * 16 + d1];
    cc += (float)ovfcnt[w];
    float inv = (cc > 0.0f) ? (1.0f / cc) : 0.0f;   // divide_no_nan
    meansb[(size_t)w * 8 + dp] = pk2(s0 * inv, s1 * inv);
}

// Fused gather + 3-layer MLP, bf16 MFMA. 512-thread blocks (8 waves) share
// ONE 32KB LDS weight copy: per CU 4 blocks x 8 waves = 32 waves (the HW
// max) vs 16 at 256-thread blocks -- the LDS cost is amortized over 2x the
// waves. __launch_bounds__(512,8) pins VGPR <= 64 (code uses 56; a spill
// would show as a FETCH_SIZE explosion).
__global__ __launch_bounds__(512, 8) void mlp_mfma_kernel(
    const float* __restrict__ X, const int* __restrict__ z0, const int* __restrict__ z1,
    const uint32_t* __restrict__ meansb,
    const float* __restrict__ W1, const float* __restrict__ b1,
    const float* __restrict__ W2, const float* __restrict__ b2,
    const float* __restrict__ Wout, const float* __restrict__ bout,
    float* __restrict__ out)
{
    __shared__ uint4 wl1[16][64];             // L1 frags: f=ct*2+ks  (16 KB)
    __shared__ uint4 wl2[16][64];             // L2 frags: f=ct*4+ks  (16 KB)

    const int lane = threadIdx.x & 63;
    const int wv = threadIdx.x >> 6;          // 0..7
    const int c = lane & 15;                  // tile-row / B-col / D-col index
    const int g = lane >> 4;                  // k-group
    const int gg = g * 8;

    // ---- build the block-shared weight fragments (4 fragment-groups per wave)
    if (wv < 4) {
        for (int f = wv * 4; f < wv * 4 + 4; f++) {
            int ct = f >> 1, ks = f & 1;
            bf16x8 fr;
#pragma unroll
            for (int e = 0; e < 8; e++)
                fr[e] = f2bf(W1[(ks * 32 + gg + e) * 128 + ct * 16 + c]);
            wl1[f][lane] = __builtin_bit_cast(uint4, fr);
        }
    } else {
        for (int f = (wv - 4) * 4; f < (wv - 4) * 4 + 4; f++) {
            int ct = f >> 2, ks = f & 3;
            bf16x8 fr;
#pragma unroll
            for (int e = 0; e < 8; e++) {
                int h = 16 * (2 * ks + (e >> 2)) + g * 4 + (e & 3);   // sigma K-map
                fr[e] = f2bf(W2[h * 64 + ct * 16 + c]);
            }
            wl2[f][lane] = __builtin_bit_cast(uint4, fr);
        }
    }
    __syncthreads();

    // b1 per-reg vectors: D1' row = hidden = ct*16 + g*4 + reg
    f32x4 b1q[8];
#pragma unroll
    for (int ct = 0; ct < 8; ct++)
        b1q[ct] = *(const f32x4*)(b1 + ct * 16 + g * 4);

    float b2v[4], wo[4];
#pragma unroll
    for (int ct = 0; ct < 4; ct++) b2v[ct] = b2[ct * 16 + c];
#pragma unroll
    for (int t = 0; t < 4; t++) wo[t] = Wout[t * 16 + c];
    const float bo = bout[0];

    // emb-gather routing for the k=32..63 fragment: g<2 -> mean0, g>=2 -> mean1
    const bool is0 = (gg < 16);
    const int* zp = is0 ? z0 : z1;
    const uint32_t* mb = meansb + (is0 ? 0 : (size_t)Q0 * 8);
    const int moffd = (g & 1) * 4;            // dword offset within bucket

    const int wave_id = blockIdx.x * 8 + wv;
    const int nw = gridDim.x * 8;
    if (wave_id >= NTILES) return;            // (never taken at this grid)

#define XPTR(t_) ((const float4*)(X + ((size_t)(t_) * 16 + c) * 32 + gg))

    // ---- pipeline prologue: tile0 data + z(tile1)
    int tile = wave_id;
    float4 xa0 = XPTR(tile)[0], xa1 = XPTR(tile)[1];
    int aA = zp[tile * 16 + c];
    uint4 mA = *(const uint4*)(mb + (size_t)aA * 8 + moffd);
    const int t1i = tile + nw;
    int aB = zp[((t1i < NTILES) ? t1i : tile) * 16 + c];

    int zoff = 0;                             // loop-variant (to the compiler) LDS offset
    for (; tile < NTILES; tile += nw) {
        asm volatile("" : "+v"(zoff));        // defeat LICM of weight loads
        const uint4* W1L = &wl1[0][0] + zoff;
        const uint4* W2L = &wl2[0][0] + zoff;

        const int t1 = tile + nw;
        const int t1c = (t1 < NTILES) ? t1 : tile;
        const int t2 = tile + 2 * nw;
        const int t2c = (t2 < NTILES) ? t2 : t1c;

        // ---- issue next-iteration loads (hidden under this tile's compute)
        float4 xb0 = XPTR(t1c)[0], xb1 = XPTR(t1c)[1];
        uint4 mB = *(const uint4*)(mb + (size_t)aB * 8 + moffd);
        int aC = zp[t2c * 16 + c];

        // ---- X / means fragments (B operand for layer 1), packed HW cvt
        bf16x8 a1[2];
        {
            uint4 u = {cvtpk(xa0.x, xa0.y), cvtpk(xa0.z, xa0.w),
                       cvtpk(xa1.x, xa1.y), cvtpk(xa1.z, xa1.w)};
            a1[0] = __builtin_bit_cast(bf16x8, u);
        }
        a1[1] = __builtin_bit_cast(bf16x8, mA);

        f32x4 d2[4];
#pragma unroll
        for (int ct = 0; ct < 4; ct++) {
            f32x4 v = {b2v[ct], b2v[ct], b2v[ct], b2v[ct]};
            d2[ct] = v;
        }

        // ---- fused layers 1+2: per ks2, produce one a2 fragment and consume it
#pragma unroll
        for (int ks2 = 0; ks2 < 4; ks2++) {
            const int cta = 2 * ks2, ctb = cta + 1;
            f32x4 aa = b1q[cta];
            aa = __builtin_amdgcn_mfma_f32_16x16x32_bf16(
                     __builtin_bit_cast(bf16x8, W1L[(cta * 2 + 0) * 64 + lane]), a1[0], aa, 0, 0, 0);
            aa = __builtin_amdgcn_mfma_f32_16x16x32_bf16(
                     __builtin_bit_cast(bf16x8, W1L[(cta * 2 + 1) * 64 + lane]), a1[1], aa, 0, 0, 0);
            f32x4 ab = b1q[ctb];
            ab = __builtin_amdgcn_mfma_f32_16x16x32_bf16(
                     __builtin_bit_cast(bf16x8, W1L[(ctb * 2 + 0) * 64 + lane]), a1[0], ab, 0, 0, 0);
            ab = __builtin_amdgcn_mfma_f32_16x16x32_bf16(
                     __builtin_bit_cast(bf16x8, W1L[(ctb * 2 + 1) * 64 + lane]), a1[1], ab, 0, 0, 0);

            bf16x8 a2v;
            {
                float r0 = fmaxf(aa[0], 0.0f), r1 = fmaxf(aa[1], 0.0f);
                float r2 = fmaxf(aa[2], 0.0f), r3 = fmaxf(aa[3], 0.0f);
                float s0 = fmaxf(ab[0], 0.0f), s1 = fmaxf(ab[1], 0.0f);
                float s2 = fmaxf(ab[2], 0.0f), s3 = fmaxf(ab[3], 0.0f);
                uint4 u = {cvtpk(r0, r1), cvtpk(r2, r3), cvtpk(s0, s1), cvtpk(s2, s3)};
                a2v = __builtin_bit_cast(bf16x8, u);
            }

#pragma unroll
            for (int ct2 = 0; ct2 < 4; ct2++)
                d2[ct2] = __builtin_amdgcn_mfma_f32_16x16x32_bf16(
                              a2v, __builtin_bit_cast(bf16x8, W2L[(ct2 * 4 + ks2) * 64 + lane]),
                              d2[ct2], 0, 0, 0);
        }

        // ---- layer 3 on VALU + 16-lane butterfly reduce + store
        float sr[4];
#pragma unroll
        for (int r = 0; r < 4; r++) {
            float s = 0.0f;
#pragma unroll
            for (int ct = 0; ct < 4; ct++)
                s = fmaf(fmaxf(d2[ct][r], 0.0f), wo[ct], s);
            sr[r] = s;
        }
#pragma unroll
        for (int m = 1; m <= 8; m <<= 1)
#pragma unroll
            for (int r = 0; r < 4; r++)
                sr[r] += __shfl_xor(sr[r], m);
        if (c == 0) {
            float4 o = {sr[0] + bo, sr[1] + bo, sr[2] + bo, sr[3] + bo};
            *(float4*)(out + tile * 16 + g * 4) = o;
        }

        // ---- rotate pipeline registers
        xa0 = xb0; xa1 = xb1; mA = mB; aB = aC;
    }
#undef XPTR
}

extern "C" void kernel_launch(void* const* d_in, const int* in_sizes, int n_in,
                              void* d_out, int out_size, void* d_ws, size_t ws_size,
                              hipStream_t stream) {
    const float* X    = (const float*)d_in[0];
    const int*   z0   = (const int*)d_in[1];
    const int*   z1   = (const int*)d_in[2];
    const float* emb0 = (const float*)d_in[3];
    const float* emb1 = (const float*)d_in[4];
    const float* W1   = (const float*)d_in[5];
    const float* b1   = (const float*)d_in[6];
    const float* W2   = (const float*)d_in[7];
    const float* b2   = (const float*)d_in[8];
    const float* Wout = (const float*)d_in[9];
    const float* bout = (const float*)d_in[10];
    float* out = (float*)d_out;
    char* ws = (char*)d_ws;

    // fixed region: cursors + ovfcnt + ovf + packed-bf16 means
    const size_t fixedB = (size_t)NPARTS * 4 + (size_t)NB * 4 + (size_t)NB * 64
                        + (size_t)NB * 32;
    // capacity ladder (deterministic host-side); overflow path keeps every rung correct
    const int c0s[4] = {6656, 5632, 5376, 0};
    const int c1s[4] = {14336, 13056, 12800, 0};
    int CAP0 = 0, CAP1 = 0, NC0 = 0, NC1 = 0, NBLK = 0;
    for (int i = 0; i < 4; i++) {
        int nc0 = (c0s[i] + CHUNK - 1) / CHUNK;
        int nc1 = (c1s[i] + CHUNK - 1) / CHUNK;
        int nblk = NP0 * nc0 + NP1 * nc1;
        size_t need = ((size_t)NP0 * c0s[i] + (size_t)NP1 * c1s[i]) * 36
                    + (size_t)nblk * PSTRIDE * 4 + fixedB;
        if (need <= ws_size) { CAP0 = c0s[i]; CAP1 = c1s[i]; NC0 = nc0; NC1 = nc1; NBLK = nblk; break; }
    }

    char* p = ws;
    uint32_t* pdata0 = (uint32_t*)p;  p += (size_t)NP0 * CAP0 * 32;
    uint32_t* pdata1 = (uint32_t*)p;  p += (size_t)NP1 * CAP1 * 32;
    uint32_t* pid0   = (uint32_t*)p;  p += (size_t)NP0 * CAP0 * 4;
    uint32_t* pid1   = (uint32_t*)p;  p += (size_t)NP1 * CAP1 * 4;
    float* partials  = (float*)p;     p += (size_t)NBLK * PSTRIDE * 4;
    uint32_t* zbase  = (uint32_t*)p;
    int* curs        = (int*)p;       p += (size_t)NPARTS * 4;
    int* ovfcnt      = (int*)p;       p += (size_t)NB * 4;
    float* ovf       = (float*)p;     p += (size_t)NB * 64;
    uint32_t* meansb = (uint32_t*)p;

    const int zero_dwords = NPARTS + NB + NB * 16;
    const size_t partA_lds = (size_t)TILE_ROWS * 36;   // sid + spay (144 KB dynamic)
    zero_ws_kernel<<<1024, 256, 0, stream>>>(zbase, zero_dwords);
    partA_kernel<<<2 * T_TILES, PA_THREADS, partA_lds, stream>>>(z0, z1, emb0, emb1,
                                                                 pid0, pdata0, pid1, pdata1,
                                                                 curs, ovfcnt, ovf, CAP0, CAP1);
    if (NBLK > 0) {
        partB_kernel<<<NBLK, 256, 0, stream>>>(pid0, pdata0, pid1, pdata1,
                                               curs, partials, CAP0, CAP1, NC0, NC1);
        combine_kernel<<<(NB * 8 + 255) / 256, 256, 0, stream>>>(partials, curs, ovfcnt,
                                                                 ovf, meansb, CAP0, CAP1,
                                                                 NC0, NC1);
    } else {
        // no-workspace fallback: means = ovf/ovfcnt only (partA sent everything to ovf)
        combine_kernel<<<(NB * 8 + 255) / 256, 256, 0, stream>>>(partials, curs, ovfcnt,
                                                                 ovf, meansb, 0, 0, 0, 0);
    }
    mlp_mfma_kernel<<<1024, 512, 0, stream>>>(X, z0, z1, meansb, W1, b1, W2, b2,
                                              Wout, bout, out);
}

// Round 24
// 81.587 us; speedup vs baseline: 1.9471x; 1.9471x over previous
//
#include <hip/hip_runtime.h>
#include <stdint.h>

#define N_ROWS 500000
#define Q0 50000
#define Q1 10000
#define NB (Q0 + Q1)
#define NTILES (N_ROWS / 16)          // 31250 exactly

// ---- partition geometry ----
#define SH0T 9                        // table0: 512-bucket partitions
#define SH1T 8                        // table1: 256-bucket partitions
#define NP0 98                        // ceil(50000/512)
#define NP1 40                        // ceil(10000/256)
#define NPARTS (NP0 + NP1)
#define TILE_ROWS 4096
#define T_TILES ((N_ROWS + TILE_ROWS - 1) / TILE_ROWS)   // 123 per table
#define PA_THREADS 512
#define ROWS_PER_T (TILE_ROWS / PA_THREADS)   // 8

#define CHUNK 2048                    // entries per partB block
#define PSTRIDE (512 * 16 + 512)      // floats per partial block (sums + counts)
#define FXS 32768.0f                  // fixed-point scale (2^15)
#define FXSI (1.0f / 32768.0f)

typedef __attribute__((ext_vector_type(8))) short bf16x8;   // 8 bf16 (4 VGPRs)
typedef __attribute__((ext_vector_type(4))) float f32x4;

static __device__ __forceinline__ uint32_t f2bfu(float f) {
    uint32_t u = __builtin_bit_cast(uint32_t, f);
    u += 0x7fffu + ((u >> 16) & 1u);          // round-to-nearest-even
    return u >> 16;
}
static __device__ __forceinline__ short f2bf(float f) { return (short)f2bfu(f); }
static __device__ __forceinline__ float bfu2f(uint32_t u) {
    return __builtin_bit_cast(float, u << 16);
}
static __device__ __forceinline__ uint32_t pk2(float x, float y) {
    return f2bfu(x) | (f2bfu(y) << 16);
}
// HW packed RNE f32->bf16 pair (T12 primitive; no builtin on gfx950 -> asm)
static __device__ __forceinline__ uint32_t cvtpk(float lo, float hi) {
    uint32_t r;
    asm("v_cvt_pk_bf16_f32 %0, %1, %2" : "=v"(r) : "v"(lo), "v"(hi));
    return r;
}

__global__ __launch_bounds__(256) void zero_ws_kernel(uint32_t* __restrict__ p, int total) {
    int stride = gridDim.x * 256;
    for (int i = blockIdx.x * 256 + threadIdx.x; i < total; i += stride) p[i] = 0u;
}

// Pass A: partition-scatter with LDS staging -> coalesced global runs.
// 4096-row tiles, 512 threads (8 waves/CU).
__global__ __launch_bounds__(PA_THREADS) void partA_kernel(const int* __restrict__ z0,
                                                    const int* __restrict__ z1,
                                                    const float* __restrict__ emb0,
                                                    const float* __restrict__ emb1,
                                                    uint32_t* __restrict__ pid0,
                                                    uint32_t* __restrict__ pdata0,
                                                    uint32_t* __restrict__ pid1,
                                                    uint32_t* __restrict__ pdata1,
                                                    int* __restrict__ curs,
                                                    int* __restrict__ ovfcnt,
                                                    float* __restrict__ ovf,
                                                    int cap0, int cap1) {
    const bool is0 = blockIdx.x < T_TILES;
    const int tile = is0 ? blockIdx.x : blockIdx.x - T_TILES;
    const int* z = is0 ? z0 : z1;
    const float* emb = is0 ? emb0 : emb1;
    const int nparts = is0 ? NP0 : NP1;
    const int SH = is0 ? SH0T : SH1T;
    const int cap = is0 ? cap0 : cap1;
    uint32_t* pid = is0 ? pid0 : pid1;
    uint32_t* pdata = is0 ? pdata0 : pdata1;
    int* cur = curs + (is0 ? 0 : NP0);
    const int wofs = is0 ? 0 : Q0;

    __shared__ int lcnt[NP0];
    __shared__ int loff[NP0 + 1];
    __shared__ int gbase[NP0];
    extern __shared__ uint32_t dynlds[];
    uint32_t* sid = dynlds;                       // TILE_ROWS
    uint32_t* spay = dynlds + TILE_ROWS;          // TILE_ROWS*8 (128 KB)

    const int t = threadIdx.x;
    const int lane = t & 63;
    const int wv = t >> 6;
    for (int i = t; i < nparts; i += PA_THREADS) lcnt[i] = 0;
    __syncthreads();

    int bks[ROWS_PER_T], rnk[ROWS_PER_T];
    const int base = tile * TILE_ROWS;
#pragma unroll
    for (int i = 0; i < ROWS_PER_T; i++) {
        int r = base + i * PA_THREADS + t;
        if (r < N_ROWS) {
            int b = z[r];
            bks[i] = b;
            rnk[i] = atomicAdd(&lcnt[b >> SH], 1);
        } else {
            bks[i] = -1;
            rnk[i] = 0;
        }
    }
    __syncthreads();

    // ---- wave 0: shfl_up inclusive scan of lcnt -> loff (two 64-wide chunks)
    //      waves 1-2: reserve global cursor space (latency overlaps the scan)
    if (wv == 0) {
        int v = (lane < nparts) ? lcnt[lane] : 0;
#pragma unroll
        for (int off = 1; off < 64; off <<= 1) {
            int u = __shfl_up(v, off);
            if (lane >= off) v += u;
        }
        if (lane < nparts) loff[lane + 1] = v;
        if (lane == 0) loff[0] = 0;
        int tot0 = __shfl(v, 63);
        if (nparts > 64) {
            int l2 = 64 + lane;
            int w2 = (l2 < nparts) ? lcnt[l2] : 0;
#pragma unroll
            for (int off = 1; off < 64; off <<= 1) {
                int u = __shfl_up(w2, off);
                if (lane >= off) w2 += u;
            }
            w2 += tot0;
            if (l2 < nparts) loff[l2 + 1] = w2;
        }
    } else if (wv < 3) {
        int p = t - 64;
        if (p < nparts) gbase[p] = atomicAdd(&cur[p], lcnt[p]);
    }
    __syncthreads();

    // ---- place entries (bf16 payload) partition-ordered in staging
#pragma unroll
    for (int i = 0; i < ROWS_PER_T; i++) {
        if (bks[i] < 0) continue;
        int r = base + i * PA_THREADS + t;
        int p = bks[i] >> SH;
        int s = loff[p] + rnk[i];
        sid[s] = (uint32_t)bks[i];
        const float4* e = (const float4*)(emb + (size_t)r * 16);
        float4 A = e[0], B = e[1], C = e[2], D = e[3];
        uint32_t* d = &spay[s * 8];
        d[0] = pk2(A.x, A.y); d[1] = pk2(A.z, A.w);
        d[2] = pk2(B.x, B.y); d[3] = pk2(B.z, B.w);
        d[4] = pk2(C.x, C.y); d[5] = pk2(C.z, C.w);
        d[6] = pk2(D.x, D.y); d[7] = pk2(D.z, D.w);
    }
    __syncthreads();

    // ---- merged flush: one thread per slot (id + 32B payload, run-coalesced)
    const int E = loff[nparts];
    for (int s = t; s < E; s += PA_THREADS) {
        int b = (int)sid[s];
        int p = b >> SH;
        int dest = gbase[p] + (s - loff[p]);
        const uint4* sp = (const uint4*)&spay[s * 8];
        uint4 lo = sp[0], hi = sp[1];
        if (dest < cap) {
            pid[(size_t)p * cap + dest] = (uint32_t)b;
            uint4* dp = (uint4*)(pdata + ((size_t)p * cap + dest) * 8);
            dp[0] = lo; dp[1] = hi;
        } else {
            atomicAdd(&ovfcnt[b + wofs], 1);
            float* o = ovf + (size_t)(b + wofs) * 16;
            uint32_t xs[8] = {lo.x, lo.y, lo.z, lo.w, hi.x, hi.y, hi.z, hi.w};
#pragma unroll
            for (int q = 0; q < 8; q++) {
                atomicAdd(o + q * 2,     bfu2f(xs[q] & 0xffffu));
                atomicAdd(o + q * 2 + 1, bfu2f(xs[q] >> 16));
            }
        }
    }
}

// Pass B: one block per (partition, CHUNK). Batched register loads, then
// INT32 fixed-point LDS accumulation via native ds_add.
__global__ __launch_bounds__(256) void partB_kernel(const uint32_t* __restrict__ pid0,
                                                    const uint32_t* __restrict__ pdata0,
                                                    const uint32_t* __restrict__ pid1,
                                                    const uint32_t* __restrict__ pdata1,
                                                    const int* __restrict__ curs,
                                                    float* __restrict__ partials,
                                                    int cap0, int cap1,
                                                    int nc0, int nc1) {
    const int bid = blockIdx.x;
    const bool is0 = bid < NP0 * nc0;
    int lp, ck;
    if (is0) { lp = bid / nc0; ck = bid % nc0; }
    else     { int r = bid - NP0 * nc0; lp = r / nc1; ck = r % nc1; }
    const int SH = is0 ? SH0T : SH1T;
    const int NBK = 1 << SH;
    const int p = is0 ? lp : NP0 + lp;
    const int cap = is0 ? cap0 : cap1;
    const uint32_t* pi = (is0 ? pid0 : pid1) + (size_t)lp * cap;
    const uint32_t* pd = (is0 ? pdata0 : pdata1) + (size_t)lp * cap * 8;
    int n = curs[p];
    if (n > cap) n = cap;
    const int start = ck * CHUNK;
    if (start >= n) return;                        // inactive chunk: never read
    const int nslots = ((start + CHUNK < n) ? CHUNK : (n - start));
    const int fb = lp << SH;

    __shared__ int sums[512 * 16];                 // 32 KB, rotation-swizzled, fixed-point
    __shared__ int cnt[512];
    const int t = threadIdx.x;
    for (int i = t; i < NBK * 16; i += 256) sums[i] = 0;
    for (int i = t; i < NBK; i += 256) cnt[i] = 0;
    __syncthreads();

    const int half = t & 1;                        // which 4 dwords of the slot
    const int sbase = t >> 1;                      // 0..127

#pragma unroll
    for (int mg = 0; mg < 2; mg++) {
        uint4 pay[8]; int lbs[8]; bool val[8];
#pragma unroll
        for (int gi = 0; gi < 8; gi++) {
            int slot = (mg * 8 + gi) * 128 + sbase;
            bool v = slot < nslots;
            val[gi] = v;
            if (v) {
                pay[gi] = *(const uint4*)(pd + (size_t)(start + slot) * 8 + half * 4);
                lbs[gi] = (int)pi[start + slot] - fb;
            }
        }
#pragma unroll
        for (int gi = 0; gi < 8; gi++) {
            if (!val[gi]) continue;
            int lb = lbs[gi];
            int* S = &sums[lb * 16];
            int d0 = half * 8;
            uint32_t xs[4] = {pay[gi].x, pay[gi].y, pay[gi].z, pay[gi].w};
#pragma unroll
            for (int jj = 0; jj < 4; jj++) {
                int da = d0 + jj * 2, db = da + 1;
                int fa = __float2int_rn(bfu2f(xs[jj] & 0xffffu) * FXS);
                int fbv = __float2int_rn(bfu2f(xs[jj] >> 16) * FXS);
                atomicAdd(S + ((da + lb) & 15), fa);
                atomicAdd(S + ((db + lb) & 15), fbv);
            }
            if (half == 0) atomicAdd(&cnt[lb], 1);
        }
    }
    __syncthreads();

    float* P = partials + (size_t)bid * PSTRIDE;
    for (int i = t; i < NBK * 16; i += 256) {
        int lb = i >> 4, d = i & 15;
        P[i] = (float)sums[lb * 16 + ((d + lb) & 15)] * FXSI;   // unswizzle + rescale
    }
    for (int i = t; i < NBK; i += 256) P[512 * 16 + i] = (float)cnt[i];
}

// Combine: one thread per (bucket, dim-PAIR). Sum chunk partials + overflow,
// divide_no_nan, write PACKED BF16 means.
__global__ __launch_bounds__(256) void combine_kernel(const float* __restrict__ partials,
                                                      const int* __restrict__ curs,
                                                      const int* __restrict__ ovfcnt,
                                                      const float* __restrict__ ovf,
                                                      uint32_t* __restrict__ meansb,
                                                      int cap0, int cap1,
                                                      int nc0, int nc1) {
    int i = blockIdx.x * 256 + threadIdx.x;
    if (i >= NB * 8) return;
    int w = i >> 3, dp = i & 7;
    int d0 = dp * 2, d1 = d0 + 1;
    const bool is0 = w < Q0;
    const int b = is0 ? w : w - Q0;
    const int lp = b >> (is0 ? SH0T : SH1T);
    const int lb = b & (is0 ? 511 : 255);
    const int p = is0 ? lp : NP0 + lp;
    const int pb = is0 ? lp * nc0 : NP0 * nc0 + lp * nc1;
    const int cap = is0 ? cap0 : cap1;
    int n = curs[p];
    if (n > cap) n = cap;
    const int nc = (n + CHUNK - 1) / CHUNK;
    float s0 = 0.0f, s1 = 0.0f, cc = 0.0f;
    for (int k = 0; k < nc; k++) {
        const float* P = partials + (size_t)(pb + k) * PSTRIDE;
        s0 += P[lb * 16 + d0];
        s1 += P[lb * 16 + d1];
        cc += P[512 * 16 + lb];
    }
    s0 += ovf[(size_t)w * 16 + d0];
    s1 += ovf[(size_t)w * 16 + d1];
    cc += (float)ovfcnt[w];
    float inv = (cc > 0.0f) ? (1.0f / cc) : 0.0f;   // divide_no_nan
    meansb[(size_t)w * 8 + dp] = pk2(s0 * inv, s1 * inv);
}

// Fused gather + 3-layer MLP, bf16 MFMA. Weight fragments live in LDS
// (one 32KB copy per block, shared by all 4 waves). A-fragment conversions
// via v_cvt_pk_bf16_f32. Grid 1024 = 4 blocks/CU exact (best measured:
// 39us). The full occupancy/ILP/register triangle has been measured:
// (256,3)+2tile=41, (256,4)+2tile=spill, (512,8)=arch/accum-split spill,
// grid1280=two-round tail -- this configuration is the local optimum.
__global__ __launch_bounds__(256, 4) void mlp_mfma_kernel(
    const float* __restrict__ X, const int* __restrict__ z0, const int* __restrict__ z1,
    const uint32_t* __restrict__ meansb,
    const float* __restrict__ W1, const float* __restrict__ b1,
    const float* __restrict__ W2, const float* __restrict__ b2,
    const float* __restrict__ Wout, const float* __restrict__ bout,
    float* __restrict__ out)
{
    __shared__ uint4 wl1[16][64];             // L1 frags: f=ct*2+ks  (16 KB)
    __shared__ uint4 wl2[16][64];             // L2 frags: f=ct*4+ks  (16 KB)

    const int lane = threadIdx.x & 63;
    const int wv = threadIdx.x >> 6;
    const int c = lane & 15;                  // tile-row / B-col / D-col index
    const int g = lane >> 4;                  // k-group
    const int gg = g * 8;

    // ---- build the block-shared weight fragments (8 fragment-groups per wave)
    if (wv < 2) {
        for (int f = wv * 8; f < wv * 8 + 8; f++) {
            int ct = f >> 1, ks = f & 1;
            bf16x8 fr;
#pragma unroll
            for (int e = 0; e < 8; e++)
                fr[e] = f2bf(W1[(ks * 32 + gg + e) * 128 + ct * 16 + c]);
            wl1[f][lane] = __builtin_bit_cast(uint4, fr);
        }
    } else {
        for (int f = (wv - 2) * 8; f < (wv - 2) * 8 + 8; f++) {
            int ct = f >> 2, ks = f & 3;
            bf16x8 fr;
#pragma unroll
            for (int e = 0; e < 8; e++) {
                int h = 16 * (2 * ks + (e >> 2)) + g * 4 + (e & 3);   // sigma K-map
                fr[e] = f2bf(W2[h * 64 + ct * 16 + c]);
            }
            wl2[f][lane] = __builtin_bit_cast(uint4, fr);
        }
    }
    __syncthreads();

    // b1 per-reg vectors: D1' row = hidden = ct*16 + g*4 + reg
    f32x4 b1q[8];
#pragma unroll
    for (int ct = 0; ct < 8; ct++)
        b1q[ct] = *(const f32x4*)(b1 + ct * 16 + g * 4);

    float b2v[4], wo[4];
#pragma unroll
    for (int ct = 0; ct < 4; ct++) b2v[ct] = b2[ct * 16 + c];
#pragma unroll
    for (int t = 0; t < 4; t++) wo[t] = Wout[t * 16 + c];
    const float bo = bout[0];

    // emb-gather routing for the k=32..63 fragment: g<2 -> mean0, g>=2 -> mean1
    const bool is0 = (gg < 16);
    const int* zp = is0 ? z0 : z1;
    const uint32_t* mb = meansb + (is0 ? 0 : (size_t)Q0 * 8);
    const int moffd = (g & 1) * 4;            // dword offset within bucket

    const int wave_id = blockIdx.x * 4 + wv;
    const int nw = gridDim.x * 4;
    if (wave_id >= NTILES) return;            // (never taken at this grid)

#define XPTR(t_) ((const float4*)(X + ((size_t)(t_) * 16 + c) * 32 + gg))

    // ---- pipeline prologue: tile0 data + z(tile1)
    int tile = wave_id;
    float4 xa0 = XPTR(tile)[0], xa1 = XPTR(tile)[1];
    int aA = zp[tile * 16 + c];
    uint4 mA = *(const uint4*)(mb + (size_t)aA * 8 + moffd);
    const int t1i = tile + nw;
    int aB = zp[((t1i < NTILES) ? t1i : tile) * 16 + c];

    int zoff = 0;                             // loop-variant (to the compiler) LDS offset
    for (; tile < NTILES; tile += nw) {
        asm volatile("" : "+v"(zoff));        // defeat LICM of weight loads
        const uint4* W1L = &wl1[0][0] + zoff;
        const uint4* W2L = &wl2[0][0] + zoff;

        const int t1 = tile + nw;
        const int t1c = (t1 < NTILES) ? t1 : tile;
        const int t2 = tile + 2 * nw;
        const int t2c = (t2 < NTILES) ? t2 : t1c;

        // ---- issue next-iteration loads (hidden under this tile's compute)
        float4 xb0 = XPTR(t1c)[0], xb1 = XPTR(t1c)[1];
        uint4 mB = *(const uint4*)(mb + (size_t)aB * 8 + moffd);
        int aC = zp[t2c * 16 + c];

        // ---- X / means fragments (B operand for layer 1), packed HW cvt
        bf16x8 a1[2];
        {
            uint4 u = {cvtpk(xa0.x, xa0.y), cvtpk(xa0.z, xa0.w),
                       cvtpk(xa1.x, xa1.y), cvtpk(xa1.z, xa1.w)};
            a1[0] = __builtin_bit_cast(bf16x8, u);
        }
        a1[1] = __builtin_bit_cast(bf16x8, mA);

        f32x4 d2[4];
#pragma unroll
        for (int ct = 0; ct < 4; ct++) {
            f32x4 v = {b2v[ct], b2v[ct], b2v[ct], b2v[ct]};
            d2[ct] = v;
        }

        // ---- fused layers 1+2: per ks2, produce one a2 fragment and consume it
#pragma unroll
        for (int ks2 = 0; ks2 < 4; ks2++) {
            const int cta = 2 * ks2, ctb = cta + 1;
            f32x4 aa = b1q[cta];
            aa = __builtin_amdgcn_mfma_f32_16x16x32_bf16(
                     __builtin_bit_cast(bf16x8, W1L[(cta * 2 + 0) * 64 + lane]), a1[0], aa, 0, 0, 0);
            aa = __builtin_amdgcn_mfma_f32_16x16x32_bf16(
                     __builtin_bit_cast(bf16x8, W1L[(cta * 2 + 1) * 64 + lane]), a1[1], aa, 0, 0, 0);
            f32x4 ab = b1q[ctb];
            ab = __builtin_amdgcn_mfma_f32_16x16x32_bf16(
                     __builtin_bit_cast(bf16x8, W1L[(ctb * 2 + 0) * 64 + lane]), a1[0], ab, 0, 0, 0);
            ab = __builtin_amdgcn_mfma_f32_16x16x32_bf16(
                     __builtin_bit_cast(bf16x8, W1L[(ctb * 2 + 1) * 64 + lane]), a1[1], ab, 0, 0, 0);

            bf16x8 a2v;
            {
                float r0 = fmaxf(aa[0], 0.0f), r1 = fmaxf(aa[1], 0.0f);
                float r2 = fmaxf(aa[2], 0.0f), r3 = fmaxf(aa[3], 0.0f);
                float s0 = fmaxf(ab[0], 0.0f), s1 = fmaxf(ab[1], 0.0f);
                float s2 = fmaxf(ab[2], 0.0f), s3 = fmaxf(ab[3], 0.0f);
                uint4 u = {cvtpk(r0, r1), cvtpk(r2, r3), cvtpk(s0, s1), cvtpk(s2, s3)};
                a2v = __builtin_bit_cast(bf16x8, u);
            }

#pragma unroll
            for (int ct2 = 0; ct2 < 4; ct2++)
                d2[ct2] = __builtin_amdgcn_mfma_f32_16x16x32_bf16(
                              a2v, __builtin_bit_cast(bf16x8, W2L[(ct2 * 4 + ks2) * 64 + lane]),
                              d2[ct2], 0, 0, 0);
        }

        // ---- layer 3 on VALU + 16-lane butterfly reduce + store
        float sr[4];
#pragma unroll
        for (int r = 0; r < 4; r++) {
            float s = 0.0f;
#pragma unroll
            for (int ct = 0; ct < 4; ct++)
                s = fmaf(fmaxf(d2[ct][r], 0.0f), wo[ct], s);
            sr[r] = s;
        }
#pragma unroll
        for (int m = 1; m <= 8; m <<= 1)
#pragma unroll
            for (int r = 0; r < 4; r++)
                sr[r] += __shfl_xor(sr[r], m);
        if (c == 0) {
            float4 o = {sr[0] + bo, sr[1] + bo, sr[2] + bo, sr[3] + bo};
            *(float4*)(out + tile * 16 + g * 4) = o;
        }

        // ---- rotate pipeline registers
        xa0 = xb0; xa1 = xb1; mA = mB; aB = aC;
    }
#undef XPTR
}

extern "C" void kernel_launch(void* const* d_in, const int* in_sizes, int n_in,
                              void* d_out, int out_size, void* d_ws, size_t ws_size,
                              hipStream_t stream) {
    const float* X    = (const float*)d_in[0];
    const int*   z0   = (const int*)d_in[1];
    const int*   z1   = (const int*)d_in[2];
    const float* emb0 = (const float*)d_in[3];
    const float* emb1 = (const float*)d_in[4];
    const float* W1   = (const float*)d_in[5];
    const float* b1   = (const float*)d_in[6];
    const float* W2   = (const float*)d_in[7];
    const float* b2   = (const float*)d_in[8];
    const float* Wout = (const float*)d_in[9];
    const float* bout = (const float*)d_in[10];
    float* out = (float*)d_out;
    char* ws = (char*)d_ws;

    // fixed region: cursors + ovfcnt + ovf + packed-bf16 means
    const size_t fixedB = (size_t)NPARTS * 4 + (size_t)NB * 4 + (size_t)NB * 64
                        + (size_t)NB * 32;
    // capacity ladder (deterministic host-side); overflow path keeps every rung correct
    const int c0s[4] = {6656, 5632, 5376, 0};
    const int c1s[4] = {14336, 13056, 12800, 0};
    int CAP0 = 0, CAP1 = 0, NC0 = 0, NC1 = 0, NBLK = 0;
    for (int i = 0; i < 4; i++) {
        int nc0 = (c0s[i] + CHUNK - 1) / CHUNK;
        int nc1 = (c1s[i] + CHUNK - 1) / CHUNK;
        int nblk = NP0 * nc0 + NP1 * nc1;
        size_t need = ((size_t)NP0 * c0s[i] + (size_t)NP1 * c1s[i]) * 36
                    + (size_t)nblk * PSTRIDE * 4 + fixedB;
        if (need <= ws_size) { CAP0 = c0s[i]; CAP1 = c1s[i]; NC0 = nc0; NC1 = nc1; NBLK = nblk; break; }
    }

    char* p = ws;
    uint32_t* pdata0 = (uint32_t*)p;  p += (size_t)NP0 * CAP0 * 32;
    uint32_t* pdata1 = (uint32_t*)p;  p += (size_t)NP1 * CAP1 * 32;
    uint32_t* pid0   = (uint32_t*)p;  p += (size_t)NP0 * CAP0 * 4;
    uint32_t* pid1   = (uint32_t*)p;  p += (size_t)NP1 * CAP1 * 4;
    float* partials  = (float*)p;     p += (size_t)NBLK * PSTRIDE * 4;
    uint32_t* zbase  = (uint32_t*)p;
    int* curs        = (int*)p;       p += (size_t)NPARTS * 4;
    int* ovfcnt      = (int*)p;       p += (size_t)NB * 4;
    float* ovf       = (float*)p;     p += (size_t)NB * 64;
    uint32_t* meansb = (uint32_t*)p;

    const int zero_dwords = NPARTS + NB + NB * 16;
    const size_t partA_lds = (size_t)TILE_ROWS * 36;   // sid + spay (144 KB dynamic)
    zero_ws_kernel<<<1024, 256, 0, stream>>>(zbase, zero_dwords);
    partA_kernel<<<2 * T_TILES, PA_THREADS, partA_lds, stream>>>(z0, z1, emb0, emb1,
                                                                 pid0, pdata0, pid1, pdata1,
                                                                 curs, ovfcnt, ovf, CAP0, CAP1);
    if (NBLK > 0) {
        partB_kernel<<<NBLK, 256, 0, stream>>>(pid0, pdata0, pid1, pdata1,
                                               curs, partials, CAP0, CAP1, NC0, NC1);
        combine_kernel<<<(NB * 8 + 255) / 256, 256, 0, stream>>>(partials, curs, ovfcnt,
                                                                 ovf, meansb, CAP0, CAP1,
                                                                 NC0, NC1);
    } else {
        // no-workspace fallback: means = ovf/ovfcnt only (partA sent everything to ovf)
        combine_kernel<<<(NB * 8 + 255) / 256, 256, 0, stream>>>(partials, curs, ovfcnt,
                                                                 ovf, meansb, 0, 0, 0, 0);
    }
    mlp_mfma_kernel<<<1024, 256, 0, stream>>>(X, z0, z1, meansb, W1, b1, W2, b2,
                                              Wout, bout, out);
}